// Round 1
// baseline (436.237 us; speedup 1.0000x reference)
//
#include <hip/hip_runtime.h>
#include <hip/hip_bf16.h>

// Problem constants
#define B_ 2
#define T_ 2048
#define C_ 1024
#define H_ 16
#define D_ 64
#define M_ROWS (B_ * T_)      // 4096
#define N_QKV (3 * C_)        // 3072

typedef __bf16 bf16x8 __attribute__((ext_vector_type(8)));
typedef float f32x4 __attribute__((ext_vector_type(4)));

// ---------------------------------------------------------------------------
// GEMM: C[M,N] = A[M,K] @ B[K,N] + bias[N]
// A: fp32 or bf16 (template), B: fp32, out: fp32 or bf16 (template)
// 128x128 block tile, BK=32, 256 threads (4 waves, each 64x64 = 4x4 MFMA tiles)
// ---------------------------------------------------------------------------
#define BM 128
#define BN 128
#define BK 32
#define LDK 40   // BK + 8 pad; row stride 80 B = 16-aligned, 2-way bank alias (free)

template <typename AT, typename OT>
__global__ __launch_bounds__(256) void gemm_bias(
    const AT* __restrict__ A, const float* __restrict__ Bm,
    const float* __restrict__ bias, OT* __restrict__ C,
    int M, int N, int K)
{
    __shared__ __bf16 As[BM * LDK];
    __shared__ __bf16 Bs[BN * LDK];   // stores B^T tile: Bs[n][k]

    const int tid  = threadIdx.x;
    const int m0   = blockIdx.x * BM;
    const int n0   = blockIdx.y * BN;
    const int w    = tid >> 6;
    const int lane = tid & 63;
    const int quad = lane >> 4;
    const int l16  = lane & 15;
    const int wr   = (w >> 1) * 64;   // wave row offset in tile
    const int wc   = (w & 1) * 64;    // wave col offset in tile

    f32x4 acc[4][4] = {};

    for (int k0 = 0; k0 < K; k0 += BK) {
        // ---- stage A tile: BM x BK (convert to bf16) ----
#pragma unroll
        for (int i = 0; i < 4; ++i) {
            int f   = i * 256 + tid;          // 1024 groups of 4 elems
            int row = f >> 3;                 // 8 groups per row
            int c4  = (f & 7) * 4;
            const AT* src = A + (size_t)(m0 + row) * K + k0 + c4;
            __bf16* dst = &As[row * LDK + c4];
            if constexpr (sizeof(AT) == 4) {
                float4 v = *(const float4*)src;
                dst[0] = (__bf16)v.x; dst[1] = (__bf16)v.y;
                dst[2] = (__bf16)v.z; dst[3] = (__bf16)v.w;
            } else {
                *(uint2*)dst = *(const uint2*)src;   // 4 bf16 = 8 B copy
            }
        }
        // ---- stage B tile: BK x BN, transposed into Bs[n][k] ----
#pragma unroll
        for (int i = 0; i < 4; ++i) {
            int f  = i * 256 + tid;
            int k  = f >> 5;                  // 32 groups per k-row
            int n4 = (f & 31) * 4;
            float4 v = *(const float4*)(Bm + (size_t)(k0 + k) * N + n0 + n4);
            Bs[(n4 + 0) * LDK + k] = (__bf16)v.x;
            Bs[(n4 + 1) * LDK + k] = (__bf16)v.y;
            Bs[(n4 + 2) * LDK + k] = (__bf16)v.z;
            Bs[(n4 + 3) * LDK + k] = (__bf16)v.w;
        }
        __syncthreads();

        bf16x8 af[4], bf[4];
#pragma unroll
        for (int mi = 0; mi < 4; ++mi)
            af[mi] = *(const bf16x8*)&As[(wr + mi * 16 + l16) * LDK + quad * 8];
#pragma unroll
        for (int ni = 0; ni < 4; ++ni)
            bf[ni] = *(const bf16x8*)&Bs[(wc + ni * 16 + l16) * LDK + quad * 8];
#pragma unroll
        for (int mi = 0; mi < 4; ++mi)
#pragma unroll
            for (int ni = 0; ni < 4; ++ni)
                acc[mi][ni] = __builtin_amdgcn_mfma_f32_16x16x32_bf16(
                    af[mi], bf[ni], acc[mi][ni], 0, 0, 0);
        __syncthreads();
    }

    // ---- epilogue: C/D layout col=lane&15, row=quad*4+r ----
#pragma unroll
    for (int mi = 0; mi < 4; ++mi) {
#pragma unroll
        for (int ni = 0; ni < 4; ++ni) {
            int col = n0 + wc + ni * 16 + l16;
            float bv = bias[col];
#pragma unroll
            for (int r = 0; r < 4; ++r) {
                int row = m0 + wr + mi * 16 + quad * 4 + r;
                C[(size_t)row * N + col] = (OT)(acc[mi][ni][r] + bv);
            }
        }
    }
}

// ---------------------------------------------------------------------------
// Flash attention: one block per (b, h, 64-query tile). 256 threads, 4 waves.
// Each wave owns 16 query rows. K/V tiles of 64 keys, online softmax.
// qkv layout: [B, T, 3C] bf16; q at col h*64, k at C + h*64, v at 2C + h*64
// out: [B, T, C] bf16 (i.e., [b][t][h*64 + d])
// ---------------------------------------------------------------------------
#define ALD 72   // 64 + 8 pad; row stride 144 B = 16-aligned

__global__ __launch_bounds__(256) void attn_kernel(
    const __bf16* __restrict__ qkv, __bf16* __restrict__ out)
{
    __shared__ __bf16 Qs[64 * ALD];
    __shared__ __bf16 Ks[64 * ALD];
    __shared__ __bf16 Vs[64 * ALD];   // transposed: Vs[d][key]
    __shared__ __bf16 Ps[64 * ALD];

    const int tid  = threadIdx.x;
    const int qt   = blockIdx.x;         // query tile 0..31
    const int bh   = blockIdx.y;         // 0..31
    const int b    = bh >> 4;
    const int h    = bh & 15;
    const int w    = tid >> 6;
    const int lane = tid & 63;
    const int quad = lane >> 4;
    const int l16  = lane & 15;

    const size_t rowStride = (size_t)N_QKV;  // 3072

    // ---- stage Q tile (64 q-rows x 64 d) ----
    {
        const size_t baseQ = ((size_t)b * T_ + qt * 64) * rowStride + (size_t)h * 64;
#pragma unroll
        for (int i = 0; i < 2; ++i) {
            int f   = i * 256 + tid;       // 512 groups of 8 bf16
            int row = f >> 3;
            int c8  = (f & 7) * 8;
            *(uint4*)&Qs[row * ALD + c8] =
                *(const uint4*)&qkv[baseQ + (size_t)row * rowStride + c8];
        }
    }

    f32x4 o_acc[4] = {};
    float m_r[4], l_r[4];
#pragma unroll
    for (int r = 0; r < 4; ++r) { m_r[r] = -1e30f; l_r[r] = 0.f; }

    __syncthreads();

    for (int kt = 0; kt <= qt; ++kt) {
        // ---- stage K tile and V tile (V transposed) ----
        {
            const size_t baseK = ((size_t)b * T_ + kt * 64) * rowStride + C_ + (size_t)h * 64;
            const size_t baseV = baseK + C_;
#pragma unroll
            for (int i = 0; i < 2; ++i) {
                int f   = i * 256 + tid;
                int row = f >> 3;          // key index
                int c8  = (f & 7) * 8;     // d offset
                *(uint4*)&Ks[row * ALD + c8] =
                    *(const uint4*)&qkv[baseK + (size_t)row * rowStride + c8];
                uint4 pv = *(const uint4*)&qkv[baseV + (size_t)row * rowStride + c8];
                const __bf16* pvb = (const __bf16*)&pv;
#pragma unroll
                for (int j = 0; j < 8; ++j)
                    Vs[(c8 + j) * ALD + row] = pvb[j];
            }
        }
        __syncthreads();

        // ---- S = Q K^T ---- wave computes rows w*16..w*16+15, all 64 keys
        f32x4 s[4] = {};
        {
            bf16x8 qf[2];
#pragma unroll
            for (int kk = 0; kk < 2; ++kk)
                qf[kk] = *(const bf16x8*)&Qs[(w * 16 + l16) * ALD + kk * 32 + quad * 8];
#pragma unroll
            for (int ni = 0; ni < 4; ++ni) {
                bf16x8 kf0 = *(const bf16x8*)&Ks[(ni * 16 + l16) * ALD + quad * 8];
                bf16x8 kf1 = *(const bf16x8*)&Ks[(ni * 16 + l16) * ALD + 32 + quad * 8];
                s[ni] = __builtin_amdgcn_mfma_f32_16x16x32_bf16(qf[0], kf0, s[ni], 0, 0, 0);
                s[ni] = __builtin_amdgcn_mfma_f32_16x16x32_bf16(qf[1], kf1, s[ni], 0, 0, 0);
            }
        }

        // ---- scale + causal mask ----
        const int rowq = qt * 64 + w * 16 + quad * 4;   // + r = global query row
#pragma unroll
        for (int ni = 0; ni < 4; ++ni)
#pragma unroll
            for (int r = 0; r < 4; ++r)
                s[ni][r] *= 0.125f;
        if (kt == qt) {
#pragma unroll
            for (int ni = 0; ni < 4; ++ni) {
                int key = kt * 64 + ni * 16 + l16;
#pragma unroll
                for (int r = 0; r < 4; ++r)
                    if (key > rowq + r) s[ni][r] = -1e30f;
            }
        }

        // ---- online softmax (per q-row; row stats live in each quad's lanes) ----
        float mx[4];
#pragma unroll
        for (int r = 0; r < 4; ++r)
            mx[r] = fmaxf(fmaxf(s[0][r], s[1][r]), fmaxf(s[2][r], s[3][r]));
#pragma unroll
        for (int off = 8; off; off >>= 1)
#pragma unroll
            for (int r = 0; r < 4; ++r)
                mx[r] = fmaxf(mx[r], __shfl_xor(mx[r], off, 64));

        float alpha[4];
#pragma unroll
        for (int r = 0; r < 4; ++r) {
            float mn = fmaxf(m_r[r], mx[r]);
            alpha[r] = __expf(m_r[r] - mn);
            m_r[r]   = mn;
        }
        float rs[4];
#pragma unroll
        for (int r = 0; r < 4; ++r) {
            float t0 = 0.f;
#pragma unroll
            for (int ni = 0; ni < 4; ++ni) {
                float p = __expf(s[ni][r] - m_r[r]);
                s[ni][r] = p;
                t0 += p;
            }
            rs[r] = t0;
        }
#pragma unroll
        for (int off = 8; off; off >>= 1)
#pragma unroll
            for (int r = 0; r < 4; ++r)
                rs[r] += __shfl_xor(rs[r], off, 64);
#pragma unroll
        for (int r = 0; r < 4; ++r)
            l_r[r] = l_r[r] * alpha[r] + rs[r];
#pragma unroll
        for (int ni = 0; ni < 4; ++ni)
#pragma unroll
            for (int r = 0; r < 4; ++r)
                o_acc[ni][r] *= alpha[r];

        // ---- P: C/D layout -> LDS -> A layout ----
#pragma unroll
        for (int ni = 0; ni < 4; ++ni)
#pragma unroll
            for (int r = 0; r < 4; ++r)
                Ps[(w * 16 + quad * 4 + r) * ALD + ni * 16 + l16] = (__bf16)s[ni][r];
        __syncthreads();

        // ---- O += P V ----
        {
            bf16x8 pf[2];
#pragma unroll
            for (int kk = 0; kk < 2; ++kk)
                pf[kk] = *(const bf16x8*)&Ps[(w * 16 + l16) * ALD + kk * 32 + quad * 8];
#pragma unroll
            for (int ni = 0; ni < 4; ++ni) {
                bf16x8 vf0 = *(const bf16x8*)&Vs[(ni * 16 + l16) * ALD + quad * 8];
                bf16x8 vf1 = *(const bf16x8*)&Vs[(ni * 16 + l16) * ALD + 32 + quad * 8];
                o_acc[ni] = __builtin_amdgcn_mfma_f32_16x16x32_bf16(pf[0], vf0, o_acc[ni], 0, 0, 0);
                o_acc[ni] = __builtin_amdgcn_mfma_f32_16x16x32_bf16(pf[1], vf1, o_acc[ni], 0, 0, 0);
            }
        }
        __syncthreads();   // protect Ks/Vs/Ps before next stage
    }

    // ---- write O (normalized) to [B,T,H*D] bf16 ----
#pragma unroll
    for (int ni = 0; ni < 4; ++ni) {
#pragma unroll
        for (int r = 0; r < 4; ++r) {
            int trow = qt * 64 + w * 16 + quad * 4 + r;
            int d    = ni * 16 + l16;
            out[((size_t)(b * T_ + trow)) * C_ + h * 64 + d] =
                (__bf16)(o_acc[ni][r] / l_r[r]);
        }
    }
}

// ---------------------------------------------------------------------------
extern "C" void kernel_launch(void* const* d_in, const int* in_sizes, int n_in,
                              void* d_out, int out_size, void* d_ws, size_t ws_size,
                              hipStream_t stream)
{
    const float* x     = (const float*)d_in[0];
    const float* Wqkv  = (const float*)d_in[1];
    const float* bqkv  = (const float*)d_in[2];
    const float* Wproj = (const float*)d_in[3];
    const float* bproj = (const float*)d_in[4];
    float* out = (float*)d_out;

    __bf16* qkv = (__bf16*)d_ws;                                   // [4096, 3072] bf16 = 25.2 MB
    __bf16* att = (__bf16*)((char*)d_ws + (size_t)M_ROWS * N_QKV * 2);  // [4096, 1024] bf16 = 8.4 MB

    // 1) qkv = x @ Wqkv + bqkv  (fp32 in, bf16 out)
    gemm_bias<float, __bf16><<<dim3(M_ROWS / BM, N_QKV / BN), 256, 0, stream>>>(
        x, Wqkv, bqkv, qkv, M_ROWS, N_QKV, C_);

    // 2) causal flash attention -> att [B,T,C] bf16
    attn_kernel<<<dim3(T_ / 64, B_ * H_), 256, 0, stream>>>(qkv, att);

    // 3) out = att @ Wproj + bproj  (bf16 in, fp32 out)
    gemm_bias<__bf16, float><<<dim3(M_ROWS / BM, C_ / BN), 256, 0, stream>>>(
        att, Wproj, bproj, out, M_ROWS, C_, C_);
}

// Round 2
// 218.171 us; speedup vs baseline: 1.9995x; 1.9995x over previous
//
#include <hip/hip_runtime.h>
#include <hip/hip_bf16.h>

// Problem constants
#define B_ 2
#define T_ 2048
#define C_ 1024
#define H_ 16
#define D_ 64
#define M_ROWS (B_ * T_)      // 4096
#define N_QKV (3 * C_)        // 3072

typedef __bf16 bf16x8 __attribute__((ext_vector_type(8)));
typedef float f32x4 __attribute__((ext_vector_type(4)));

// async global->LDS, 16B per lane. LDS dest = wave-uniform base + lane*16.
__device__ __forceinline__ void gl_lds16(const __bf16* g, __bf16* l) {
    __builtin_amdgcn_global_load_lds(
        (const __attribute__((address_space(1))) unsigned int*)g,
        (__attribute__((address_space(3))) unsigned int*)l, 16, 0, 0);
}

// ---------------------------------------------------------------------------
// Pre-pass 1: fp32 -> bf16 convert (x -> xb). 8 elems/thread.
// ---------------------------------------------------------------------------
__global__ __launch_bounds__(256) void conv_bf16(const float* __restrict__ in,
                                                 __bf16* __restrict__ out, int n8)
{
    int i = blockIdx.x * 256 + threadIdx.x;
    if (i >= n8) return;
    const float4* p = (const float4*)(in + (size_t)i * 8);
    float4 a = p[0], b = p[1];
    __bf16 v[8] = {(__bf16)a.x, (__bf16)a.y, (__bf16)a.z, (__bf16)a.w,
                   (__bf16)b.x, (__bf16)b.y, (__bf16)b.z, (__bf16)b.w};
    *(uint4*)(out + (size_t)i * 8) = *(uint4*)v;
}

// ---------------------------------------------------------------------------
// Pre-pass 2: W [K][N] fp32 -> Wt [N][K] bf16 (transpose + convert). 64x64 tiles.
// grid: (K/64, N/64)
// ---------------------------------------------------------------------------
__global__ __launch_bounds__(256) void transp_w(const float* __restrict__ W,
                                                __bf16* __restrict__ Wt, int K, int N)
{
    __shared__ __bf16 Ts[64 * 72];   // Ts[n][k]
    const int tid = threadIdx.x;
    const int k0 = blockIdx.x * 64, n0 = blockIdx.y * 64;
#pragma unroll
    for (int i = 0; i < 4; ++i) {
        int f = i * 256 + tid;
        int r = f >> 4, c4 = (f & 15) * 4;
        float4 v = *(const float4*)(W + (size_t)(k0 + r) * N + n0 + c4);
        Ts[(c4 + 0) * 72 + r] = (__bf16)v.x;
        Ts[(c4 + 1) * 72 + r] = (__bf16)v.y;
        Ts[(c4 + 2) * 72 + r] = (__bf16)v.z;
        Ts[(c4 + 3) * 72 + r] = (__bf16)v.w;
    }
    __syncthreads();
#pragma unroll
    for (int i = 0; i < 2; ++i) {
        int f = i * 256 + tid;
        int n = f >> 3, c8 = (f & 7) * 8;
        *(uint4*)(Wt + (size_t)(n0 + n) * K + k0 + c8) = *(const uint4*)&Ts[n * 72 + c8];
    }
}

// ---------------------------------------------------------------------------
// Pre-pass 3: v-part of qkv -> vt [B*H*D][T] bf16 (per-head transpose).
// grid: (M_ROWS/64, C_/64). qkv row stride = 3072, v at col 2048.
// ---------------------------------------------------------------------------
__global__ __launch_bounds__(256) void transp_v(const __bf16* __restrict__ qkv,
                                                __bf16* __restrict__ vt)
{
    __shared__ __bf16 Ts[64 * 72];   // Ts[c][t]
    const int tid = threadIdx.x;
    const int gx = blockIdx.x, gy = blockIdx.y;
#pragma unroll
    for (int i = 0; i < 2; ++i) {
        int f = i * 256 + tid;
        int r = f >> 3, c8 = (f & 7) * 8;
        uint4 v = *(const uint4*)(qkv + (size_t)(gx * 64 + r) * N_QKV + 2 * C_ + gy * 64 + c8);
        const __bf16* vb = (const __bf16*)&v;
#pragma unroll
        for (int j = 0; j < 8; ++j) Ts[(c8 + j) * 72 + r] = vb[j];
    }
    __syncthreads();
    const int b = gx >> 5;                 // 2048 rows per batch, 32 tiles
    const int tbase = (gx & 31) * 64;
#pragma unroll
    for (int i = 0; i < 2; ++i) {
        int f = i * 256 + tid;
        int c = f >> 3, t8 = (f & 7) * 8;
        *(uint4*)(vt + ((size_t)b * C_ + gy * 64 + c) * T_ + tbase + t8) =
            *(const uint4*)&Ts[c * 72 + t8];
    }
}

// ---------------------------------------------------------------------------
// m97-style GEMM: C[M,N] = A[M,K]bf16 @ Bt[N,K]bf16^T + bias
// 128x128 tile, BK=64, global_load_lds(16B) staging, XOR-swizzled LDS.
// ---------------------------------------------------------------------------
#define GBK 64

template <typename OT>
__global__ __launch_bounds__(256) void gemm_bt(
    const __bf16* __restrict__ A, const __bf16* __restrict__ Bt,
    const float* __restrict__ bias, OT* __restrict__ C,
    int M, int N, int K)
{
    __shared__ __bf16 As[128 * GBK];
    __shared__ __bf16 Bs[128 * GBK];

    const int tid  = threadIdx.x;
    const int m0   = blockIdx.x * 128;
    const int n0   = blockIdx.y * 128;
    const int w    = tid >> 6;
    const int lane = tid & 63;
    const int quad = lane >> 4;
    const int l16  = lane & 15;
    const int wr   = (w >> 1) * 64;
    const int wc   = (w & 1) * 64;

    // staging: wave w covers rows w*32..w*32+31, 4 issues of 8 rows.
    // lane l -> row +(l>>3), physical seg (l&7) holds logical seg (l&7)^(l>>3).
    const int srow = w * 32 + (lane >> 3);
    const int sseg = ((lane & 7) ^ (lane >> 3)) * 8;   // element offset
    const __bf16* Ag = A + (size_t)(m0 + srow) * K + sseg;
    const __bf16* Bg = Bt + (size_t)(n0 + srow) * K + sseg;

    f32x4 acc[4][4] = {};

    for (int k0 = 0; k0 < K; k0 += GBK) {
#pragma unroll
        for (int i = 0; i < 4; ++i) {
            gl_lds16(Ag + k0 + (size_t)(i * 8) * K, &As[(w * 32 + i * 8) * GBK]);
            gl_lds16(Bg + k0 + (size_t)(i * 8) * K, &Bs[(w * 32 + i * 8) * GBK]);
        }
        __syncthreads();
#pragma unroll
        for (int kk = 0; kk < 2; ++kk) {
            bf16x8 af[4], bf[4];
#pragma unroll
            for (int mi = 0; mi < 4; ++mi)
                af[mi] = *(const bf16x8*)&As[(wr + mi * 16 + l16) * GBK +
                                             (((kk * 4 + quad) ^ (l16 & 7)) * 8)];
#pragma unroll
            for (int ni = 0; ni < 4; ++ni)
                bf[ni] = *(const bf16x8*)&Bs[(wc + ni * 16 + l16) * GBK +
                                             (((kk * 4 + quad) ^ (l16 & 7)) * 8)];
#pragma unroll
            for (int mi = 0; mi < 4; ++mi)
#pragma unroll
                for (int ni = 0; ni < 4; ++ni)
                    acc[mi][ni] = __builtin_amdgcn_mfma_f32_16x16x32_bf16(
                        af[mi], bf[ni], acc[mi][ni], 0, 0, 0);
        }
        __syncthreads();
    }

#pragma unroll
    for (int mi = 0; mi < 4; ++mi) {
#pragma unroll
        for (int ni = 0; ni < 4; ++ni) {
            int col = n0 + wc + ni * 16 + l16;
            float bv = bias[col];
#pragma unroll
            for (int r = 0; r < 4; ++r) {
                int row = m0 + wr + mi * 16 + quad * 4 + r;
                C[(size_t)row * N + col] = (OT)(acc[mi][ni][r] + bv);
            }
        }
    }
}

// ---------------------------------------------------------------------------
// Flash attention, balanced: block = (pair p, bh); runs qt=p then qt=31-p
// -> every block does exactly 33 K-tile iterations.
// Staging via global_load_lds, XOR-swizzled unpadded LDS. Ps is wave-private.
// ---------------------------------------------------------------------------
#define PLD 72

__global__ __launch_bounds__(256) void attn_kernel(
    const __bf16* __restrict__ qkv, const __bf16* __restrict__ vt,
    __bf16* __restrict__ out)
{
    __shared__ __bf16 Qs[64 * 64];
    __shared__ __bf16 Ks[64 * 64];
    __shared__ __bf16 Vs[64 * 64];        // Vs[d][key], swizzled
    __shared__ __bf16 Ps[4][16 * PLD];    // per-wave, padded (no swizzle)

    const int tid  = threadIdx.x;
    const int p    = blockIdx.x;          // 0..15
    const int bh   = blockIdx.y;          // 0..31
    const int b    = bh >> 4;
    const int h    = bh & 15;
    const int w    = tid >> 6;
    const int lane = tid & 63;
    const int quad = lane >> 4;
    const int l16  = lane & 15;

    const int srow = (lane >> 3);                      // 0..7 within 8-row issue
    const int sseg = ((lane & 7) ^ (lane >> 3)) * 8;   // swizzled element offset
    __bf16* Psw = &Ps[w][0];

    for (int half = 0; half < 2; ++half) {
        const int qt = half ? (31 - p) : p;

        // ---- stage Q tile (rows w*16..w*16+15 per wave) ----
        {
            const __bf16* Qg = qkv + (size_t)(b * T_ + qt * 64 + w * 16 + srow) * N_QKV
                             + (size_t)h * 64 + sseg;
            gl_lds16(Qg, &Qs[(w * 16) * 64]);
            gl_lds16(Qg + (size_t)8 * N_QKV, &Qs[(w * 16 + 8) * 64]);
        }

        f32x4 o_acc[4] = {};
        float m_r[4], l_r[4];
#pragma unroll
        for (int r = 0; r < 4; ++r) { m_r[r] = -1e30f; l_r[r] = 0.f; }

        for (int kt = 0; kt <= qt; ++kt) {
            // ---- stage K tile + Vt tile ----
            {
                const __bf16* Kg = qkv + (size_t)(b * T_ + kt * 64 + w * 16 + srow) * N_QKV
                                 + C_ + (size_t)h * 64 + sseg;
                gl_lds16(Kg, &Ks[(w * 16) * 64]);
                gl_lds16(Kg + (size_t)8 * N_QKV, &Ks[(w * 16 + 8) * 64]);
                const __bf16* Vg = vt + ((size_t)(b * H_ + h) * 64 + w * 16 + srow) * T_
                                 + kt * 64 + sseg;
                gl_lds16(Vg, &Vs[(w * 16) * 64]);
                gl_lds16(Vg + (size_t)8 * T_, &Vs[(w * 16 + 8) * 64]);
            }
            __syncthreads();

            // ---- S = Q K^T ----
            f32x4 s[4] = {};
            {
                bf16x8 qf[2];
#pragma unroll
                for (int kk = 0; kk < 2; ++kk)
                    qf[kk] = *(const bf16x8*)&Qs[(w * 16 + l16) * 64 +
                                                 (((kk * 4 + quad) ^ (l16 & 7)) * 8)];
#pragma unroll
                for (int ni = 0; ni < 4; ++ni) {
#pragma unroll
                    for (int kk = 0; kk < 2; ++kk) {
                        bf16x8 kf = *(const bf16x8*)&Ks[(ni * 16 + l16) * 64 +
                                                        (((kk * 4 + quad) ^ (l16 & 7)) * 8)];
                        s[ni] = __builtin_amdgcn_mfma_f32_16x16x32_bf16(qf[kk], kf, s[ni], 0, 0, 0);
                    }
                }
            }

            // ---- scale + causal mask ----
            const int rowq = qt * 64 + w * 16 + quad * 4;
#pragma unroll
            for (int ni = 0; ni < 4; ++ni)
#pragma unroll
                for (int r = 0; r < 4; ++r)
                    s[ni][r] *= 0.125f;
            if (kt == qt) {
#pragma unroll
                for (int ni = 0; ni < 4; ++ni) {
                    int key = kt * 64 + ni * 16 + l16;
#pragma unroll
                    for (int r = 0; r < 4; ++r)
                        if (key > rowq + r) s[ni][r] = -1e30f;
                }
            }

            // ---- online softmax (row stats across l16 within quad) ----
            float mx[4];
#pragma unroll
            for (int r = 0; r < 4; ++r)
                mx[r] = fmaxf(fmaxf(s[0][r], s[1][r]), fmaxf(s[2][r], s[3][r]));
#pragma unroll
            for (int off = 8; off; off >>= 1)
#pragma unroll
                for (int r = 0; r < 4; ++r)
                    mx[r] = fmaxf(mx[r], __shfl_xor(mx[r], off, 64));

            float alpha[4];
#pragma unroll
            for (int r = 0; r < 4; ++r) {
                float mn = fmaxf(m_r[r], mx[r]);
                alpha[r] = __expf(m_r[r] - mn);
                m_r[r]   = mn;
            }
            float rs[4];
#pragma unroll
            for (int r = 0; r < 4; ++r) {
                float t0 = 0.f;
#pragma unroll
                for (int ni = 0; ni < 4; ++ni) {
                    float pe = __expf(s[ni][r] - m_r[r]);
                    s[ni][r] = pe;
                    t0 += pe;
                }
                rs[r] = t0;
            }
#pragma unroll
            for (int off = 8; off; off >>= 1)
#pragma unroll
                for (int r = 0; r < 4; ++r)
                    rs[r] += __shfl_xor(rs[r], off, 64);
#pragma unroll
            for (int r = 0; r < 4; ++r)
                l_r[r] = l_r[r] * alpha[r] + rs[r];
#pragma unroll
            for (int ni = 0; ni < 4; ++ni)
#pragma unroll
                for (int r = 0; r < 4; ++r)
                    o_acc[ni][r] *= alpha[r];

            // ---- P: C/D layout -> wave-private LDS -> A layout ----
#pragma unroll
            for (int ni = 0; ni < 4; ++ni)
#pragma unroll
                for (int r = 0; r < 4; ++r)
                    Psw[(quad * 4 + r) * PLD + ni * 16 + l16] = (__bf16)s[ni][r];
            __threadfence_block();   // wave-private: lgkm drain, no barrier needed

            // ---- O += P V ----
            {
                bf16x8 pf[2];
#pragma unroll
                for (int kk = 0; kk < 2; ++kk)
                    pf[kk] = *(const bf16x8*)&Psw[l16 * PLD + kk * 32 + quad * 8];
#pragma unroll
                for (int ni = 0; ni < 4; ++ni) {
#pragma unroll
                    for (int kk = 0; kk < 2; ++kk) {
                        bf16x8 vf = *(const bf16x8*)&Vs[(ni * 16 + l16) * 64 +
                                                        (((kk * 4 + quad) ^ (l16 & 7)) * 8)];
                        o_acc[ni] = __builtin_amdgcn_mfma_f32_16x16x32_bf16(pf[kk], vf, o_acc[ni], 0, 0, 0);
                    }
                }
            }
            __syncthreads();   // all waves done with Ks/Vs before restage
        }

        // ---- write O ----
#pragma unroll
        for (int ni = 0; ni < 4; ++ni) {
#pragma unroll
            for (int r = 0; r < 4; ++r) {
                int trow = qt * 64 + w * 16 + quad * 4 + r;
                out[((size_t)(b * T_ + trow)) * C_ + h * 64 + ni * 16 + l16] =
                    (__bf16)(o_acc[ni][r] / l_r[r]);
            }
        }
    }
}

// ---------------------------------------------------------------------------
extern "C" void kernel_launch(void* const* d_in, const int* in_sizes, int n_in,
                              void* d_out, int out_size, void* d_ws, size_t ws_size,
                              hipStream_t stream)
{
    const float* x     = (const float*)d_in[0];
    const float* Wqkv  = (const float*)d_in[1];
    const float* bqkv  = (const float*)d_in[2];
    const float* Wproj = (const float*)d_in[3];
    const float* bproj = (const float*)d_in[4];
    float* out = (float*)d_out;

    char* ws = (char*)d_ws;
    __bf16* xb     = (__bf16*)(ws);                          //  8 MB [4096,1024] (reused as att)
    __bf16* Wqkvt  = (__bf16*)(ws + (8u << 20));             //  6 MB [3072,1024]
    __bf16* Wprojt = (__bf16*)(ws + (14u << 20));            //  2 MB [1024,1024]
    __bf16* qkv    = (__bf16*)(ws + (16u << 20));            // 24 MB [4096,3072]
    __bf16* vt     = (__bf16*)(ws + (40u << 20));            //  8 MB [B*H*64,2048]
    __bf16* att    = xb;                                     // alias: xb dead after GEMM1

    // pre-passes
    conv_bf16<<<(M_ROWS * C_ / 8 + 255) / 256, 256, 0, stream>>>(x, xb, M_ROWS * C_ / 8);
    transp_w<<<dim3(C_ / 64, N_QKV / 64), 256, 0, stream>>>(Wqkv, Wqkvt, C_, N_QKV);
    transp_w<<<dim3(C_ / 64, C_ / 64), 256, 0, stream>>>(Wproj, Wprojt, C_, C_);

    // 1) qkv = xb @ Wqkvt^T + bqkv
    gemm_bt<__bf16><<<dim3(M_ROWS / 128, N_QKV / 128), 256, 0, stream>>>(
        xb, Wqkvt, bqkv, qkv, M_ROWS, N_QKV, C_);

    // 2) transpose v part -> vt
    transp_v<<<dim3(M_ROWS / 64, C_ / 64), 256, 0, stream>>>(qkv, vt);

    // 3) balanced causal flash attention
    attn_kernel<<<dim3(16, B_ * H_), 256, 0, stream>>>(qkv, vt, att);

    // 4) out = att @ Wprojt^T + bproj
    gemm_bt<float><<<dim3(M_ROWS / 128, C_ / 128), 256, 0, stream>>>(
        att, Wprojt, bproj, out, M_ROWS, C_, C_);
}

// Round 3
// 187.076 us; speedup vs baseline: 2.3319x; 1.1662x over previous
//
#include <hip/hip_runtime.h>
#include <hip/hip_bf16.h>

// Problem constants
#define B_ 2
#define T_ 2048
#define C_ 1024
#define H_ 16
#define D_ 64
#define M_ROWS (B_ * T_)      // 4096
#define N_QKV (3 * C_)        // 3072

typedef __bf16 bf16x8 __attribute__((ext_vector_type(8)));
typedef float f32x4 __attribute__((ext_vector_type(4)));

// 0.125 (1/sqrt(64)) * log2(e): softmax done in base-2, scale folded in.
#define SC 0.18033688011112042f

// async global->LDS, 16B per lane. LDS dest = wave-uniform base + lane*16.
__device__ __forceinline__ void gl_lds16(const __bf16* g, __bf16* l) {
    __builtin_amdgcn_global_load_lds(
        (const __attribute__((address_space(1))) unsigned int*)g,
        (__attribute__((address_space(3))) unsigned int*)l, 16, 0, 0);
}

// ---------------------------------------------------------------------------
// Pre-pass 1: fp32 -> bf16 convert (x -> xb). 8 elems/thread.
// ---------------------------------------------------------------------------
__global__ __launch_bounds__(256) void conv_bf16(const float* __restrict__ in,
                                                 __bf16* __restrict__ out, int n8)
{
    int i = blockIdx.x * 256 + threadIdx.x;
    if (i >= n8) return;
    const float4* p = (const float4*)(in + (size_t)i * 8);
    float4 a = p[0], b = p[1];
    __bf16 v[8] = {(__bf16)a.x, (__bf16)a.y, (__bf16)a.z, (__bf16)a.w,
                   (__bf16)b.x, (__bf16)b.y, (__bf16)b.z, (__bf16)b.w};
    *(uint4*)(out + (size_t)i * 8) = *(uint4*)v;
}

// ---------------------------------------------------------------------------
// Pre-pass 2: W [K][N] fp32 -> Wt [N][K] bf16 (transpose + convert). 64x64 tiles.
// ---------------------------------------------------------------------------
__global__ __launch_bounds__(256) void transp_w(const float* __restrict__ W,
                                                __bf16* __restrict__ Wt, int K, int N)
{
    __shared__ __bf16 Ts[64 * 72];   // Ts[n][k]
    const int tid = threadIdx.x;
    const int k0 = blockIdx.x * 64, n0 = blockIdx.y * 64;
#pragma unroll
    for (int i = 0; i < 4; ++i) {
        int f = i * 256 + tid;
        int r = f >> 4, c4 = (f & 15) * 4;
        float4 v = *(const float4*)(W + (size_t)(k0 + r) * N + n0 + c4);
        Ts[(c4 + 0) * 72 + r] = (__bf16)v.x;
        Ts[(c4 + 1) * 72 + r] = (__bf16)v.y;
        Ts[(c4 + 2) * 72 + r] = (__bf16)v.z;
        Ts[(c4 + 3) * 72 + r] = (__bf16)v.w;
    }
    __syncthreads();
#pragma unroll
    for (int i = 0; i < 2; ++i) {
        int f = i * 256 + tid;
        int n = f >> 3, c8 = (f & 7) * 8;
        *(uint4*)(Wt + (size_t)(n0 + n) * K + k0 + c8) = *(const uint4*)&Ts[n * 72 + c8];
    }
}

// ---------------------------------------------------------------------------
// Pre-pass 3: v-part of qkv -> vt [B*H*D][T] bf16 (per-head transpose).
// ---------------------------------------------------------------------------
__global__ __launch_bounds__(256) void transp_v(const __bf16* __restrict__ qkv,
                                                __bf16* __restrict__ vt)
{
    __shared__ __bf16 Ts[64 * 72];   // Ts[c][t]
    const int tid = threadIdx.x;
    const int gx = blockIdx.x, gy = blockIdx.y;
#pragma unroll
    for (int i = 0; i < 2; ++i) {
        int f = i * 256 + tid;
        int r = f >> 3, c8 = (f & 7) * 8;
        uint4 v = *(const uint4*)(qkv + (size_t)(gx * 64 + r) * N_QKV + 2 * C_ + gy * 64 + c8);
        const __bf16* vb = (const __bf16*)&v;
#pragma unroll
        for (int j = 0; j < 8; ++j) Ts[(c8 + j) * 72 + r] = vb[j];
    }
    __syncthreads();
    const int b = gx >> 5;
    const int tbase = (gx & 31) * 64;
#pragma unroll
    for (int i = 0; i < 2; ++i) {
        int f = i * 256 + tid;
        int c = f >> 3, t8 = (f & 7) * 8;
        *(uint4*)(vt + ((size_t)b * C_ + gy * 64 + c) * T_ + tbase + t8) =
            *(const uint4*)&Ts[c * 72 + t8];
    }
}

// ---------------------------------------------------------------------------
// m97-style GEMM: C[M,N] = A[M,K]bf16 @ Bt[N,K]bf16^T + bias
// ---------------------------------------------------------------------------
#define GBK 64

template <typename OT>
__global__ __launch_bounds__(256) void gemm_bt(
    const __bf16* __restrict__ A, const __bf16* __restrict__ Bt,
    const float* __restrict__ bias, OT* __restrict__ C,
    int M, int N, int K)
{
    __shared__ __bf16 As[128 * GBK];
    __shared__ __bf16 Bs[128 * GBK];

    const int tid  = threadIdx.x;
    const int m0   = blockIdx.x * 128;
    const int n0   = blockIdx.y * 128;
    const int w    = tid >> 6;
    const int lane = tid & 63;
    const int quad = lane >> 4;
    const int l16  = lane & 15;
    const int wr   = (w >> 1) * 64;
    const int wc   = (w & 1) * 64;

    const int srow = w * 32 + (lane >> 3);
    const int sseg = ((lane & 7) ^ (lane >> 3)) * 8;
    const __bf16* Ag = A + (size_t)(m0 + srow) * K + sseg;
    const __bf16* Bg = Bt + (size_t)(n0 + srow) * K + sseg;

    f32x4 acc[4][4] = {};

    for (int k0 = 0; k0 < K; k0 += GBK) {
#pragma unroll
        for (int i = 0; i < 4; ++i) {
            gl_lds16(Ag + k0 + (size_t)(i * 8) * K, &As[(w * 32 + i * 8) * GBK]);
            gl_lds16(Bg + k0 + (size_t)(i * 8) * K, &Bs[(w * 32 + i * 8) * GBK]);
        }
        __syncthreads();
#pragma unroll
        for (int kk = 0; kk < 2; ++kk) {
            bf16x8 af[4], bf[4];
#pragma unroll
            for (int mi = 0; mi < 4; ++mi)
                af[mi] = *(const bf16x8*)&As[(wr + mi * 16 + l16) * GBK +
                                             (((kk * 4 + quad) ^ (l16 & 7)) * 8)];
#pragma unroll
            for (int ni = 0; ni < 4; ++ni)
                bf[ni] = *(const bf16x8*)&Bs[(wc + ni * 16 + l16) * GBK +
                                             (((kk * 4 + quad) ^ (l16 & 7)) * 8)];
#pragma unroll
            for (int mi = 0; mi < 4; ++mi)
#pragma unroll
                for (int ni = 0; ni < 4; ++ni)
                    acc[mi][ni] = __builtin_amdgcn_mfma_f32_16x16x32_bf16(
                        af[mi], bf[ni], acc[mi][ni], 0, 0, 0);
        }
        __syncthreads();
    }

#pragma unroll
    for (int mi = 0; mi < 4; ++mi) {
#pragma unroll
        for (int ni = 0; ni < 4; ++ni) {
            int col = n0 + wc + ni * 16 + l16;
            float bv = bias[col];
#pragma unroll
            for (int r = 0; r < 4; ++r) {
                int row = m0 + wr + mi * 16 + quad * 4 + r;
                C[(size_t)row * N + col] = (OT)(acc[mi][ni][r] + bv);
            }
        }
    }
}

// ---------------------------------------------------------------------------
// Flash attention v3: balanced pairs, no-max base-2 softmax, S^T trick,
// double-buffered K/V staging (1 barrier per K-tile), hoisted Q fragments.
// Each wave owns 16 q-rows; S^T = mfma(K_frag, Q_frag) puts q in the lane
// dim so P packs with 4x ds_write_b64 and l is a per-lane scalar.
// ---------------------------------------------------------------------------
__global__ __launch_bounds__(256) void attn_kernel(
    const __bf16* __restrict__ qkv, const __bf16* __restrict__ vt,
    __bf16* __restrict__ out)
{
    __shared__ __bf16 Qs[64 * 64];
    __shared__ __bf16 KVs[4][64 * 64];   // K0,V0,K1,V1 (double buffer)
    __shared__ __bf16 Ps[4][16 * 64];    // per-wave P, XOR-swizzled

    const int tid  = threadIdx.x;
    const int p    = blockIdx.x;          // 0..15 (pair index)
    const int bh   = blockIdx.y;          // 0..31
    const int b    = bh >> 4;
    const int h    = bh & 15;
    const int w    = tid >> 6;
    const int lane = tid & 63;
    const int quad = lane >> 4;
    const int l16  = lane & 15;
    const int lxor = l16 & 7;

    const int srow = lane >> 3;
    const int sseg = ((lane & 7) ^ srow) * 8;
    __bf16* Psw = &Ps[w][0];

    for (int half = 0; half < 2; ++half) {
        const int qt = half ? (31 - p) : p;

        // ---- stage Q tile + K/V tile 0 ----
        {
            const __bf16* Qg = qkv + (size_t)(b * T_ + qt * 64 + w * 16 + srow) * N_QKV
                             + (size_t)h * 64 + sseg;
            gl_lds16(Qg, &Qs[(w * 16) * 64]);
            gl_lds16(Qg + (size_t)8 * N_QKV, &Qs[(w * 16 + 8) * 64]);
            const __bf16* Kg = qkv + (size_t)(b * T_ + w * 16 + srow) * N_QKV
                             + C_ + (size_t)h * 64 + sseg;
            gl_lds16(Kg, &KVs[0][(w * 16) * 64]);
            gl_lds16(Kg + (size_t)8 * N_QKV, &KVs[0][(w * 16 + 8) * 64]);
            const __bf16* Vg = vt + ((size_t)(b * H_ + h) * 64 + w * 16 + srow) * T_ + sseg;
            gl_lds16(Vg, &KVs[1][(w * 16) * 64]);
            gl_lds16(Vg + (size_t)8 * T_, &KVs[1][(w * 16 + 8) * 64]);
        }
        __syncthreads();

        // ---- hoist Q fragments (B-operand: n = q = w*16+l16, k = d) ----
        bf16x8 qf[2];
#pragma unroll
        for (int kk = 0; kk < 2; ++kk)
            qf[kk] = *(const bf16x8*)&Qs[(w * 16 + l16) * 64 + (((kk * 4 + quad) ^ lxor) * 8)];

        f32x4 o[4] = {};
        float lacc = 0.f;

        for (int kt = 0; kt <= qt; ++kt) {
            const __bf16* Ks = KVs[(kt & 1) * 2];
            const __bf16* Vs = KVs[(kt & 1) * 2 + 1];

            // prefetch next K/V tile into other buffer (async, drains at barrier)
            if (kt < qt) {
                int nb = ((kt + 1) & 1) * 2;
                const __bf16* Kg = qkv + (size_t)(b * T_ + (kt + 1) * 64 + w * 16 + srow) * N_QKV
                                 + C_ + (size_t)h * 64 + sseg;
                gl_lds16(Kg, &KVs[nb][(w * 16) * 64]);
                gl_lds16(Kg + (size_t)8 * N_QKV, &KVs[nb][(w * 16 + 8) * 64]);
                const __bf16* Vg = vt + ((size_t)(b * H_ + h) * 64 + w * 16 + srow) * T_
                                 + (kt + 1) * 64 + sseg;
                gl_lds16(Vg, &KVs[nb + 1][(w * 16) * 64]);
                gl_lds16(Vg + (size_t)8 * T_, &KVs[nb + 1][(w * 16 + 8) * 64]);
            }

            // ---- S^T = K Q^T: lane holds q = w*16+l16 (col), keys ni*16+quad*4+r (row)
            f32x4 s[4] = {};
#pragma unroll
            for (int ni = 0; ni < 4; ++ni) {
#pragma unroll
                for (int kk = 0; kk < 2; ++kk) {
                    bf16x8 kf = *(const bf16x8*)&Ks[(ni * 16 + l16) * 64 +
                                                    (((kk * 4 + quad) ^ lxor) * 8)];
                    s[ni] = __builtin_amdgcn_mfma_f32_16x16x32_bf16(kf, qf[kk], s[ni], 0, 0, 0);
                }
            }

            // ---- causal mask (diag tile only): key > q -> -inf ----
            if (kt == qt) {
#pragma unroll
                for (int ni = 0; ni < 4; ++ni)
#pragma unroll
                    for (int r = 0; r < 4; ++r)
                        if (ni * 16 + quad * 4 + r > w * 16 + l16) s[ni][r] = -3.0e38f;
            }

            // ---- p = 2^(s*SC); accumulate l; pack to bf16; write P to LDS ----
#pragma unroll
            for (int ni = 0; ni < 4; ++ni) {
                __bf16 pb[4];
#pragma unroll
                for (int r = 0; r < 4; ++r) {
                    float pe = __builtin_amdgcn_exp2f(s[ni][r] * SC);
                    lacc += pe;
                    pb[r] = (__bf16)pe;
                }
                // logical byte offset in row: ni*32 + quad*8 -> seg = ni*2+(quad>>1)
                int seg = (ni * 2 + (quad >> 1)) ^ lxor;
                *(uint2*)&Psw[l16 * 64 + seg * 8 + (quad & 1) * 4] = *(uint2*)pb;
            }
            __threadfence_block();   // wave-private write->read ordering (lgkmcnt)

            // ---- O += P V : A = P[q=l16][key], B = V[key][d=l16-col] ----
            bf16x8 pf[2];
#pragma unroll
            for (int kk = 0; kk < 2; ++kk)
                pf[kk] = *(const bf16x8*)&Psw[l16 * 64 + (((kk * 4 + quad) ^ lxor) * 8)];
#pragma unroll
            for (int ni = 0; ni < 4; ++ni) {
#pragma unroll
                for (int kk = 0; kk < 2; ++kk) {
                    bf16x8 vf = *(const bf16x8*)&Vs[(ni * 16 + l16) * 64 +
                                                    (((kk * 4 + quad) ^ lxor) * 8)];
                    o[ni] = __builtin_amdgcn_mfma_f32_16x16x32_bf16(pf[kk], vf, o[ni], 0, 0, 0);
                }
            }
            __syncthreads();   // buffers consumed; prefetched tile drained
        }

        // ---- reduce l across quads (q = w*16+l16 lane-constant) ----
        lacc += __shfl_xor(lacc, 16, 64);
        lacc += __shfl_xor(lacc, 32, 64);

        // ---- epilogue: O row q = w*16+quad*4+r, col d = ni*16+l16 ----
#pragma unroll
        for (int r = 0; r < 4; ++r) {
            float linv = 1.f / __shfl(lacc, quad * 4 + r, 64);
            int trow = qt * 64 + w * 16 + quad * 4 + r;
#pragma unroll
            for (int ni = 0; ni < 4; ++ni)
                out[((size_t)(b * T_ + trow)) * C_ + h * 64 + ni * 16 + l16] =
                    (__bf16)(o[ni][r] * linv);
        }
        // no barrier needed: next half's staging touches LDS no wave still reads
    }
}

// ---------------------------------------------------------------------------
extern "C" void kernel_launch(void* const* d_in, const int* in_sizes, int n_in,
                              void* d_out, int out_size, void* d_ws, size_t ws_size,
                              hipStream_t stream)
{
    const float* x     = (const float*)d_in[0];
    const float* Wqkv  = (const float*)d_in[1];
    const float* bqkv  = (const float*)d_in[2];
    const float* Wproj = (const float*)d_in[3];
    const float* bproj = (const float*)d_in[4];
    float* out = (float*)d_out;

    char* ws = (char*)d_ws;
    __bf16* xb     = (__bf16*)(ws);                          //  8 MB [4096,1024] (reused as att)
    __bf16* Wqkvt  = (__bf16*)(ws + (8u << 20));             //  6 MB [3072,1024]
    __bf16* Wprojt = (__bf16*)(ws + (14u << 20));            //  2 MB [1024,1024]
    __bf16* qkv    = (__bf16*)(ws + (16u << 20));            // 24 MB [4096,3072]
    __bf16* vt     = (__bf16*)(ws + (40u << 20));            //  8 MB [B*H*64,2048]
    __bf16* att    = xb;                                     // alias: xb dead after GEMM1

    conv_bf16<<<(M_ROWS * C_ / 8 + 255) / 256, 256, 0, stream>>>(x, xb, M_ROWS * C_ / 8);
    transp_w<<<dim3(C_ / 64, N_QKV / 64), 256, 0, stream>>>(Wqkv, Wqkvt, C_, N_QKV);
    transp_w<<<dim3(C_ / 64, C_ / 64), 256, 0, stream>>>(Wproj, Wprojt, C_, C_);

    gemm_bt<__bf16><<<dim3(M_ROWS / 128, N_QKV / 128), 256, 0, stream>>>(
        xb, Wqkvt, bqkv, qkv, M_ROWS, N_QKV, C_);

    transp_v<<<dim3(M_ROWS / 64, C_ / 64), 256, 0, stream>>>(qkv, vt);

    attn_kernel<<<dim3(16, B_ * H_), 256, 0, stream>>>(qkv, vt, att);

    gemm_bt<float><<<dim3(M_ROWS / 128, C_ / 128), 256, 0, stream>>>(
        att, Wprojt, bproj, out, M_ROWS, C_, C_);
}